// Round 5
// baseline (1099.677 us; speedup 1.0000x reference)
//
#include <hip/hip_runtime.h>
#include <hip/hip_bf16.h>
#include <hip/hip_cooperative_groups.h>

namespace cg = cooperative_groups;

// Problem constants
constexpr int Bn  = 128;   // batch
constexpr int Ln  = 200;   // sentences
constexpr int D2n = 1024;  // 2*SH
constexpr int G3n = 1536;  // 3*EH
constexpr int Tn  = 3;
constexpr int Nn  = 512;   // A (attention dim) == d_proj cols
constexpr int Kn  = 1024;  // d_proj K

typedef unsigned short ushort;
typedef float f32x4 __attribute__((ext_vector_type(4)));
typedef __bf16 bf16x8 __attribute__((ext_vector_type(8)));

__device__ __forceinline__ ushort f2bf(float f) {   // RNE float->bf16
  unsigned u = __float_as_uint(f);
  unsigned r = (u + 0x7fffu + ((u >> 16) & 1u)) >> 16;
  return (ushort)r;
}
__device__ __forceinline__ float bf2f(ushort h) {
  return __uint_as_float(((unsigned)h) << 16);
}

__device__ __forceinline__ void gld_lds16(const ushort* g, ushort* l) {
  __builtin_amdgcn_global_load_lds(
      (const __attribute__((address_space(1))) unsigned int*)g,
      (__attribute__((address_space(3))) unsigned int*)l, 16, 0, 0);
}

// ---------------------------------------------------------------------------
// gather last_back = sent[:, 0, 512:1024]
__global__ void k_gather_lastb(const float* __restrict__ sent, float* __restrict__ lastb) {
  int i = blockIdx.x * 256 + threadIdx.x;        // 65536 = 128*512
  int b = i >> 9, k = i & 511;
  lastb[i] = sent[(size_t)b * (Ln * D2n) + 512 + k];
}

// ---------------------------------------------------------------------------
// split fp32 -> hi/lo bf16 (used for both wd [512x1024] and sent [25600x1024])
__global__ void k_split(const float* __restrict__ W, ushort* __restrict__ hi,
                        ushort* __restrict__ lo) {
  int i = blockIdx.x * 256 + threadIdx.x;        // float4 index
  float4 v = ((const float4*)W)[i];
  ushort4 h, l;
  h.x = f2bf(v.x); l.x = f2bf(v.x - bf2f(h.x));
  h.y = f2bf(v.y); l.y = f2bf(v.y - bf2f(h.y));
  h.z = f2bf(v.z); l.z = f2bf(v.z - bf2f(h.z));
  h.w = f2bf(v.w); l.w = f2bf(v.w - bf2f(h.w));
  ((ushort4*)hi)[i] = h;
  ((ushort4*)lo)[i] = l;
}

// ---------------------------------------------------------------------------
// small GEMM body (R3-proven): out[b,j] = act(bias[j] + sum_k in[b,k]*W[j,k])
// 16 b-rows staged in LDS, 64 j per block-work, 4 b per wave.
template<int K, int ACT>
__device__ __forceinline__ void gemm_work(const float* __restrict__ in,
                                          const float* __restrict__ W,
                                          const float* __restrict__ bias,
                                          float* __restrict__ out, int J,
                                          int jt, int bt, float* s) {
  const int tid = threadIdx.x;
  const int b0 = bt * 16;
  const int jl = tid & 63;
  const int j  = jt * 64 + jl;
  const int bg = (tid >> 6) * 4;                 // 0,4,8,12

  const float4* inp4 = (const float4*)(in + (size_t)b0 * K);
  float4* s4 = (float4*)s;
  for (int i = tid; i < 4 * K; i += 256) s4[i] = inp4[i];
  __syncthreads();

  const float4* w4 = (const float4*)(W + (size_t)j * K);
  const float4* r0 = (const float4*)(s + (size_t)(bg + 0) * K);
  const float4* r1 = (const float4*)(s + (size_t)(bg + 1) * K);
  const float4* r2 = (const float4*)(s + (size_t)(bg + 2) * K);
  const float4* r3 = (const float4*)(s + (size_t)(bg + 3) * K);

  float acc0 = 0.f, acc1 = 0.f, acc2 = 0.f, acc3 = 0.f;
  #pragma unroll 4
  for (int k4 = 0; k4 < K / 4; ++k4) {
    float4 wv = w4[k4];
    float4 a;
    a = r0[k4]; acc0 += wv.x*a.x + wv.y*a.y + wv.z*a.z + wv.w*a.w;
    a = r1[k4]; acc1 += wv.x*a.x + wv.y*a.y + wv.z*a.z + wv.w*a.w;
    a = r2[k4]; acc2 += wv.x*a.x + wv.y*a.y + wv.z*a.z + wv.w*a.w;
    a = r3[k4]; acc3 += wv.x*a.x + wv.y*a.y + wv.z*a.z + wv.w*a.w;
  }
  float bb = bias[j];
  float v;
  v = acc0 + bb; if (ACT) v = tanhf(v); out[(size_t)(b0 + bg + 0) * J + j] = v;
  v = acc1 + bb; if (ACT) v = tanhf(v); out[(size_t)(b0 + bg + 1) * J + j] = v;
  v = acc2 + bb; if (ACT) v = tanhf(v); out[(size_t)(b0 + bg + 2) * J + j] = v;
  v = acc3 + bb; if (ACT) v = tanhf(v); out[(size_t)(b0 + bg + 3) * J + j] = v;
  __syncthreads();                               // LDS safe for next work
}

// standalone small gemm for the preamble h0 computation
template<int K, int ACT>
__launch_bounds__(256)
__global__ void k_small_gemm(const float* __restrict__ in, const float* __restrict__ W,
                             const float* __restrict__ bias, float* __restrict__ out, int J) {
  __shared__ float s[16 * K];
  gemm_work<K, ACT>(in, W, bias, out, J, blockIdx.x, blockIdx.y, s);
}

// ---------------------------------------------------------------------------
// d_proj = sent @ wd^T + bd via split-bf16 MFMA (unchanged since R3: ~108us,
// MfmaUtil ~31%, 0 conflicts, FETCH ~112MB -- control group)
constexpr int NSTEP = Kn / 32;   // 32

__launch_bounds__(256)
__global__ void k_dproj_mfma(const ushort* __restrict__ Ahi, const ushort* __restrict__ Alo,
                             const ushort* __restrict__ Whi, const ushort* __restrict__ Wlo,
                             const float* __restrict__ bias, float* __restrict__ C) {
  __shared__ __align__(16) ushort sAh[128 * 32];
  __shared__ __align__(16) ushort sAl[128 * 32];
  __shared__ __align__(16) ushort sBh[128 * 32];
  __shared__ __align__(16) ushort sBl[128 * 32];

  const int bid = blockIdx.x;
  const int m0  = (bid % 200) * 128;
  const int n0  = (bid / 200) * 128;

  const int tid  = threadIdx.x;
  const int wave = tid >> 6, lane = tid & 63;
  const int wy = (wave >> 1) * 64, wx = (wave & 1) * 64;
  const int lm = lane & 15, lq = lane >> 4;

  const int fs = (lq ^ ((lm >> 1) & 3)) * 8;     // swizzled 16B slot

  const int S0 = (wave * 2 + 0) * 64 + lane;
  const int S1 = (wave * 2 + 1) * 64 + lane;
  const int r0 = S0 >> 2, r1 = S1 >> 2;
  const int c0 = ((S0 & 3) ^ ((r0 >> 1) & 3)) * 8;
  const int c1 = ((S1 & 3) ^ ((r1 >> 1) & 3)) * 8;
  const ushort* pAh0 = Ahi + (size_t)(m0 + r0) * Kn + c0;
  const ushort* pAh1 = Ahi + (size_t)(m0 + r1) * Kn + c1;
  const ushort* pAl0 = Alo + (size_t)(m0 + r0) * Kn + c0;
  const ushort* pAl1 = Alo + (size_t)(m0 + r1) * Kn + c1;
  const ushort* pBh0 = Whi + (size_t)(n0 + r0) * Kn + c0;
  const ushort* pBh1 = Whi + (size_t)(n0 + r1) * Kn + c1;
  const ushort* pBl0 = Wlo + (size_t)(n0 + r0) * Kn + c0;
  const ushort* pBl1 = Wlo + (size_t)(n0 + r1) * Kn + c1;
  ushort* dA0 = &sAh[S0 * 8]; ushort* dA1 = &sAh[S1 * 8];
  ushort* dL0 = &sAl[S0 * 8]; ushort* dL1 = &sAl[S1 * 8];
  ushort* dB0 = &sBh[S0 * 8]; ushort* dB1 = &sBh[S1 * 8];
  ushort* dC0 = &sBl[S0 * 8]; ushort* dC1 = &sBl[S1 * 8];

  f32x4 acc[4][4] = {};

  for (int ks = 0; ks < NSTEP; ++ks) {
    const int ko = ks * 32;
    gld_lds16(pAh0 + ko, dA0); gld_lds16(pAh1 + ko, dA1);
    gld_lds16(pAl0 + ko, dL0); gld_lds16(pAl1 + ko, dL1);
    gld_lds16(pBh0 + ko, dB0); gld_lds16(pBh1 + ko, dB1);
    gld_lds16(pBl0 + ko, dC0); gld_lds16(pBl1 + ko, dC1);
    __syncthreads();

    bf16x8 ah[4], al[4], bh[4], bl[4];
    #pragma unroll
    for (int mi = 0; mi < 4; ++mi) {
      const int o = (wy + mi * 16 + lm) * 32 + fs;
      ah[mi] = *(const bf16x8*)&sAh[o];
      al[mi] = *(const bf16x8*)&sAl[o];
    }
    #pragma unroll
    for (int ni = 0; ni < 4; ++ni) {
      const int o = (wx + ni * 16 + lm) * 32 + fs;
      bh[ni] = *(const bf16x8*)&sBh[o];
      bl[ni] = *(const bf16x8*)&sBl[o];
    }
    #pragma unroll
    for (int mi = 0; mi < 4; ++mi)
      #pragma unroll
      for (int ni = 0; ni < 4; ++ni) {
        acc[mi][ni] = __builtin_amdgcn_mfma_f32_16x16x32_bf16(ah[mi], bh[ni], acc[mi][ni], 0, 0, 0);
        acc[mi][ni] = __builtin_amdgcn_mfma_f32_16x16x32_bf16(ah[mi], bl[ni], acc[mi][ni], 0, 0, 0);
        acc[mi][ni] = __builtin_amdgcn_mfma_f32_16x16x32_bf16(al[mi], bh[ni], acc[mi][ni], 0, 0, 0);
      }
    __syncthreads();
  }

  #pragma unroll
  for (int ni = 0; ni < 4; ++ni) {
    int col = n0 + wx + ni * 16 + lm;
    float bb = bias[col];
    #pragma unroll
    for (int mi = 0; mi < 4; ++mi) {
      int rbase = m0 + wy + mi * 16 + lq * 4;
      #pragma unroll
      for (int r = 0; r < 4; ++r)
        C[(size_t)(rbase + r) * Nn + col] = acc[mi][ni][r] + bb;
    }
  }
}

// ---------------------------------------------------------------------------
// Fused T-loop: the 3 selection iterations in ONE cooperative kernel.
// Grid 256 blocks x 256 threads (1/CU, co-resident), grid.sync() between
// phases. Phase bodies are verbatim R3 kernels, grid-strided:
//   A: gx = s_row@w_ih^T (192 works) + gh = h@w_hh^T (192 works)
//   B: GRU pointwise (65536 elems)
//   C: q = h@wq^T + bq (64 works)
//   D: score (6400 works, wave per row)
//   E: argmax scan + select + mask (128 works)
__launch_bounds__(256)
__global__ void k_tloop(const float* __restrict__ sent,
                        const float* __restrict__ w_ih, const float* __restrict__ w_hh,
                        const float* __restrict__ b_ih, const float* __restrict__ b_hh,
                        const float* __restrict__ wq, const float* __restrict__ bq,
                        const float* __restrict__ wsv, const float* __restrict__ bsv,
                        const float* __restrict__ dproj,
                        float* __restrict__ s_row, float* __restrict__ h,
                        float* __restrict__ gx, float* __restrict__ gh,
                        float* __restrict__ q, float* __restrict__ scoresf,
                        int* __restrict__ mask,
                        float* __restrict__ outScores, float* __restrict__ outSel) {
  cg::grid_group grid = cg::this_grid();
  __shared__ float sbuf[16 * 1024];              // 64 KB, reused by A/C
  __shared__ int s_idx;

  const int bid = blockIdx.x;
  const int tid = threadIdx.x;

  for (int t = 0; t < Tn; ++t) {
    // ---- A: gx (K=1024) and gh (K=512) -----------------------------------
    for (int w = bid; w < 384; w += 256) {
      if (w < 192) gemm_work<1024, 0>(s_row, w_ih, b_ih, gx, G3n, w % 24, w / 24, sbuf);
      else { int v = w - 192; gemm_work<512, 0>(h, w_hh, b_hh, gh, G3n, v % 24, v / 24, sbuf); }
    }
    grid.sync();

    // ---- B: GRU pointwise h = (1-z)*n + z*h ------------------------------
    {
      int i = bid * 256 + tid;                   // 65536 exactly
      int b = i >> 9, j = i & 511;
      const float* gxb = gx + (size_t)b * G3n;
      const float* ghb = gh + (size_t)b * G3n;
      float rg = 1.f / (1.f + expf(-(gxb[j] + ghb[j])));
      float zg = 1.f / (1.f + expf(-(gxb[512 + j] + ghb[512 + j])));
      float ng = tanhf(gxb[1024 + j] + rg * ghb[1024 + j]);
      h[i] = (1.f - zg) * ng + zg * h[i];
    }
    grid.sync();

    // ---- C: q = h @ wq^T + bq --------------------------------------------
    for (int w = bid; w < 64; w += 256)
      gemm_work<512, 0>(h, wq, bq, q, 512, w % 8, w / 8, sbuf);
    grid.sync();

    // ---- D: score --------------------------------------------------------
    for (int blk = bid; blk < 6400; blk += 256) {
      int w = blk * 4 + (tid >> 6);              // 0..25599
      int lane = tid & 63;
      int b = w / Ln, l = w % Ln;
      const float4* dp4 = (const float4*)(dproj + (size_t)w * Nn);
      const float4* q4  = (const float4*)(q + (size_t)b * Nn);
      const float4* ws4 = (const float4*)wsv;

      float sum = 0.f;
      #pragma unroll
      for (int i = 0; i < 2; ++i) {
        int idx = lane + i * 64;                 // 128 float4 per row
        float4 d = dp4[idx], qq = q4[idx], wv = ws4[idx];
        sum += tanhf(qq.x + d.x) * wv.x + tanhf(qq.y + d.y) * wv.y
             + tanhf(qq.z + d.z) * wv.z + tanhf(qq.w + d.w) * wv.w;
      }
      #pragma unroll
      for (int off = 32; off > 0; off >>= 1) sum += __shfl_xor(sum, off, 64);

      if (lane == 0) {
        float v = sum + bsv[0];
        if (mask[w]) v = -1000000.0f;
        scoresf[w] = v;
        outScores[(size_t)b * (Tn * Ln) + t * Ln + l] = v;
      }
    }
    grid.sync();

    // ---- E: argmax (first-index tie-break) + select + mask ---------------
    for (int b = bid; b < 128; b += 256) {
      if (tid < 64) {
        const float* sc = scoresf + (size_t)b * Ln;
        float best = -3.0e38f; int bi = 0;
        for (int l = tid; l < Ln; l += 64) {
          float v = sc[l];
          if (v > best) { best = v; bi = l; }    // increasing l: strict > keeps first
        }
        #pragma unroll
        for (int off = 32; off > 0; off >>= 1) {
          float ov = __shfl_down(best, off, 64);
          int   oi = __shfl_down(bi,   off, 64);
          if (ov > best || (ov == best && oi < bi)) { best = ov; bi = oi; }
        }
        if (tid == 0) s_idx = bi;
      }
      __syncthreads();
      int idx = s_idx;
      const float* src = sent + ((size_t)b * Ln + idx) * D2n;
      float* dstp = s_row + (size_t)b * D2n;
      int k = tid * 4;                           // 256 threads x 4 = 1024
      *(float4*)(dstp + k) = *(const float4*)(src + k);
      if (tid == 0) {
        mask[b * Ln + idx] = 1;
        outSel[(size_t)b * Tn + t] = (float)idx;
      }
      __syncthreads();
    }
    grid.sync();
  }
}

// ---------------------------------------------------------------------------
extern "C" void kernel_launch(void* const* d_in, const int* in_sizes, int n_in,
                              void* d_out, int out_size, void* d_ws, size_t ws_size,
                              hipStream_t stream) {
  const float* sent = (const float*)d_in[0];
  const float* h0_w = (const float*)d_in[1];
  const float* h0_b = (const float*)d_in[2];
  const float* w_ih = (const float*)d_in[3];
  const float* w_hh = (const float*)d_in[4];
  const float* b_ih = (const float*)d_in[5];
  const float* b_hh = (const float*)d_in[6];
  const float* wq   = (const float*)d_in[7];
  const float* bq   = (const float*)d_in[8];
  const float* wd   = (const float*)d_in[9];
  const float* bd   = (const float*)d_in[10];
  const float* wsv  = (const float*)d_in[11];
  const float* bsv  = (const float*)d_in[12];

  float* wsf     = (float*)d_ws;
  float* d_proj  = wsf;                       // 25600*512 = 13107200
  float* s_row   = d_proj + 13107200;         // 128*1024
  float* h       = s_row + 131072;            // 128*512
  float* gx      = h + 65536;                 // 128*1536
  float* gh      = gx + 196608;               // 128*1536
  float* lastb   = gh + 196608;               // 128*512
  float* q       = lastb + 65536;             // 128*512
  float* scoresf = q + 65536;                 // 128*200
  int*   mask    = (int*)(scoresf + 25600);   // 128*200 ints
  ushort* Whi    = (ushort*)(mask + 25600);   // 512*1024 shorts
  ushort* Wlo    = Whi + 524288;              // 512*1024 shorts
  ushort* Ahi    = Wlo + 524288;              // 25600*1024 shorts
  ushort* Alo    = Ahi + 26214400;            // 25600*1024 shorts

  float* outScores = (float*)d_out;                       // (B, T, L) fp32
  float* outSel    = outScores + (size_t)Bn * Tn * Ln;    // (B, T) fp32

  hipMemsetAsync(s_row, 0, 131072 * sizeof(float), stream);       // s_prev(t=0) = 0
  hipMemsetAsync(mask, 0, 25600 * sizeof(int), stream);

  k_gather_lastb<<<256, 256, 0, stream>>>(sent, lastb);
  k_small_gemm<512, 1><<<dim3(8, 8), 256, 0, stream>>>(lastb, h0_w, h0_b, h, 512);
  k_split<<<512, 256, 0, stream>>>(wd, Whi, Wlo);         // 512*1024/4 float4
  k_split<<<25600, 256, 0, stream>>>(sent, Ahi, Alo);     // 25600*1024/4 float4
  k_dproj_mfma<<<800, 256, 0, stream>>>(Ahi, Alo, Whi, Wlo, bd, d_proj);

  void* args[] = {
    (void*)&sent, (void*)&w_ih, (void*)&w_hh, (void*)&b_ih, (void*)&b_hh,
    (void*)&wq, (void*)&bq, (void*)&wsv, (void*)&bsv, (void*)&d_proj,
    (void*)&s_row, (void*)&h, (void*)&gx, (void*)&gh, (void*)&q,
    (void*)&scoresf, (void*)&mask, (void*)&outScores, (void*)&outSel
  };
  hipLaunchCooperativeKernel((void*)k_tloop, dim3(256), dim3(256), args, 0, stream);
}

// Round 7
// 592.650 us; speedup vs baseline: 1.8555x; 1.8555x over previous
//
#include <hip/hip_runtime.h>
#include <hip/hip_bf16.h>

// Problem constants
constexpr int Bn  = 128;   // batch
constexpr int Ln  = 200;   // sentences
constexpr int D2n = 1024;  // 2*SH
constexpr int G3n = 1536;  // 3*EH
constexpr int Tn  = 3;
constexpr int Nn  = 512;   // A (attention dim) == d_proj cols
constexpr int Kn  = 1024;  // d_proj K

typedef unsigned short ushort;
typedef float f32x4 __attribute__((ext_vector_type(4)));
typedef __bf16 bf16x8 __attribute__((ext_vector_type(8)));

__device__ __forceinline__ ushort f2bf(float f) {   // RNE float->bf16
  unsigned u = __float_as_uint(f);
  unsigned r = (u + 0x7fffu + ((u >> 16) & 1u)) >> 16;
  return (ushort)r;
}
__device__ __forceinline__ float bf2f(ushort h) {
  return __uint_as_float(((unsigned)h) << 16);
}

__device__ __forceinline__ void gld_lds16(const ushort* g, ushort* l) {
  __builtin_amdgcn_global_load_lds(
      (const __attribute__((address_space(1))) unsigned int*)g,
      (__attribute__((address_space(3))) unsigned int*)l, 16, 0, 0);
}

// ---------------------------------------------------------------------------
// gather last_back = sent[:, 0, 512:1024]
__global__ void k_gather_lastb(const float* __restrict__ sent, float* __restrict__ lastb) {
  int i = blockIdx.x * 256 + threadIdx.x;        // 65536 = 128*512
  int b = i >> 9, k = i & 511;
  lastb[i] = sent[(size_t)b * (Ln * D2n) + 512 + k];
}

// ---------------------------------------------------------------------------
// split fp32 -> hi/lo bf16 (weights, sent, h)
__global__ void k_split(const float* __restrict__ W, ushort* __restrict__ hi,
                        ushort* __restrict__ lo) {
  int i = blockIdx.x * 256 + threadIdx.x;        // float4 index
  float4 v = ((const float4*)W)[i];
  ushort4 h, l;
  h.x = f2bf(v.x); l.x = f2bf(v.x - bf2f(h.x));
  h.y = f2bf(v.y); l.y = f2bf(v.y - bf2f(h.y));
  h.z = f2bf(v.z); l.z = f2bf(v.z - bf2f(h.z));
  h.w = f2bf(v.w); l.w = f2bf(v.w - bf2f(h.w));
  ((ushort4*)hi)[i] = h;
  ((ushort4*)lo)[i] = l;
}

// ---------------------------------------------------------------------------
// small GEMM (preamble h0 only): out[b,j] = act(bias[j] + sum_k in[b,k]*W[j,k])
template<int K, int ACT>
__launch_bounds__(256)
__global__ void k_small_gemm(const float* __restrict__ in, const float* __restrict__ W,
                             const float* __restrict__ bias, float* __restrict__ out, int J) {
  __shared__ float s[16 * K];
  const int b0 = blockIdx.y * 16;
  const int jl = threadIdx.x & 63;
  const int j  = blockIdx.x * 64 + jl;
  const int bg = (threadIdx.x >> 6) * 4;

  const float4* inp4 = (const float4*)(in + (size_t)b0 * K);
  float4* s4 = (float4*)s;
  for (int i = threadIdx.x; i < 4 * K; i += 256) s4[i] = inp4[i];
  __syncthreads();

  const float4* w4 = (const float4*)(W + (size_t)j * K);
  const float4* r0 = (const float4*)(s + (size_t)(bg + 0) * K);
  const float4* r1 = (const float4*)(s + (size_t)(bg + 1) * K);
  const float4* r2 = (const float4*)(s + (size_t)(bg + 2) * K);
  const float4* r3 = (const float4*)(s + (size_t)(bg + 3) * K);

  float acc0 = 0.f, acc1 = 0.f, acc2 = 0.f, acc3 = 0.f;
  #pragma unroll 4
  for (int k4 = 0; k4 < K / 4; ++k4) {
    float4 wv = w4[k4];
    float4 a;
    a = r0[k4]; acc0 += wv.x*a.x + wv.y*a.y + wv.z*a.z + wv.w*a.w;
    a = r1[k4]; acc1 += wv.x*a.x + wv.y*a.y + wv.z*a.z + wv.w*a.w;
    a = r2[k4]; acc2 += wv.x*a.x + wv.y*a.y + wv.z*a.z + wv.w*a.w;
    a = r3[k4]; acc3 += wv.x*a.x + wv.y*a.y + wv.z*a.z + wv.w*a.w;
  }
  float bb = bias[j];
  float v;
  v = acc0 + bb; if (ACT) v = tanhf(v); out[(size_t)(b0 + bg + 0) * J + j] = v;
  v = acc1 + bb; if (ACT) v = tanhf(v); out[(size_t)(b0 + bg + 1) * J + j] = v;
  v = acc2 + bb; if (ACT) v = tanhf(v); out[(size_t)(b0 + bg + 2) * J + j] = v;
  v = acc3 + bb; if (ACT) v = tanhf(v); out[(size_t)(b0 + bg + 3) * J + j] = v;
}

// ---------------------------------------------------------------------------
// Shared 128x128-tile split-bf16 MFMA body (proven: 0 bank conflicts).
// C[m0..m0+128, n0..n0+128] = A[128 x KK] * B[128 x KK]^T + bias
template<int KK>
__device__ __forceinline__ void mfma_tile128(
    const ushort* __restrict__ Ah, const ushort* __restrict__ Al,
    const ushort* __restrict__ Bh, const ushort* __restrict__ Bl,
    const float* __restrict__ bias, float* __restrict__ C, int ldc,
    int m0, int n0) {
  __shared__ __align__(16) ushort sAh[128 * 32];
  __shared__ __align__(16) ushort sAl[128 * 32];
  __shared__ __align__(16) ushort sBh[128 * 32];
  __shared__ __align__(16) ushort sBl[128 * 32];

  const int tid  = threadIdx.x;
  const int wave = tid >> 6, lane = tid & 63;
  const int wy = (wave >> 1) * 64, wx = (wave & 1) * 64;
  const int lm = lane & 15, lq = lane >> 4;
  const int fs = (lq ^ ((lm >> 1) & 3)) * 8;     // swizzled 16B slot

  const int S0 = (wave * 2 + 0) * 64 + lane;
  const int S1 = (wave * 2 + 1) * 64 + lane;
  const int r0 = S0 >> 2, r1 = S1 >> 2;
  const int c0 = ((S0 & 3) ^ ((r0 >> 1) & 3)) * 8;
  const int c1 = ((S1 & 3) ^ ((r1 >> 1) & 3)) * 8;
  const ushort* pAh0 = Ah + (size_t)(m0 + r0) * KK + c0;
  const ushort* pAh1 = Ah + (size_t)(m0 + r1) * KK + c1;
  const ushort* pAl0 = Al + (size_t)(m0 + r0) * KK + c0;
  const ushort* pAl1 = Al + (size_t)(m0 + r1) * KK + c1;
  const ushort* pBh0 = Bh + (size_t)(n0 + r0) * KK + c0;
  const ushort* pBh1 = Bh + (size_t)(n0 + r1) * KK + c1;
  const ushort* pBl0 = Bl + (size_t)(n0 + r0) * KK + c0;
  const ushort* pBl1 = Bl + (size_t)(n0 + r1) * KK + c1;
  ushort* dA0 = &sAh[S0 * 8]; ushort* dA1 = &sAh[S1 * 8];
  ushort* dL0 = &sAl[S0 * 8]; ushort* dL1 = &sAl[S1 * 8];
  ushort* dB0 = &sBh[S0 * 8]; ushort* dB1 = &sBh[S1 * 8];
  ushort* dC0 = &sBl[S0 * 8]; ushort* dC1 = &sBl[S1 * 8];

  f32x4 acc[4][4] = {};

  for (int ks = 0; ks < KK / 32; ++ks) {
    const int ko = ks * 32;
    gld_lds16(pAh0 + ko, dA0); gld_lds16(pAh1 + ko, dA1);
    gld_lds16(pAl0 + ko, dL0); gld_lds16(pAl1 + ko, dL1);
    gld_lds16(pBh0 + ko, dB0); gld_lds16(pBh1 + ko, dB1);
    gld_lds16(pBl0 + ko, dC0); gld_lds16(pBl1 + ko, dC1);
    __syncthreads();

    bf16x8 ah[4], al[4], bh[4], bl[4];
    #pragma unroll
    for (int mi = 0; mi < 4; ++mi) {
      const int o = (wy + mi * 16 + lm) * 32 + fs;
      ah[mi] = *(const bf16x8*)&sAh[o];
      al[mi] = *(const bf16x8*)&sAl[o];
    }
    #pragma unroll
    for (int ni = 0; ni < 4; ++ni) {
      const int o = (wx + ni * 16 + lm) * 32 + fs;
      bh[ni] = *(const bf16x8*)&sBh[o];
      bl[ni] = *(const bf16x8*)&sBl[o];
    }
    #pragma unroll
    for (int mi = 0; mi < 4; ++mi)
      #pragma unroll
      for (int ni = 0; ni < 4; ++ni) {
        acc[mi][ni] = __builtin_amdgcn_mfma_f32_16x16x32_bf16(ah[mi], bh[ni], acc[mi][ni], 0, 0, 0);
        acc[mi][ni] = __builtin_amdgcn_mfma_f32_16x16x32_bf16(ah[mi], bl[ni], acc[mi][ni], 0, 0, 0);
        acc[mi][ni] = __builtin_amdgcn_mfma_f32_16x16x32_bf16(al[mi], bh[ni], acc[mi][ni], 0, 0, 0);
      }
    __syncthreads();
  }

  #pragma unroll
  for (int ni = 0; ni < 4; ++ni) {
    int col = n0 + wx + ni * 16 + lm;
    float bb = bias[col];
    #pragma unroll
    for (int mi = 0; mi < 4; ++mi) {
      int rbase = m0 + wy + mi * 16 + lq * 4;
      #pragma unroll
      for (int r = 0; r < 4; ++r)
        C[(size_t)(rbase + r) * ldc + col] = acc[mi][ni][r] + bb;
    }
  }
}

__launch_bounds__(256)
__global__ void k_dproj_mfma(const ushort* __restrict__ Ahi, const ushort* __restrict__ Alo,
                             const ushort* __restrict__ Whi, const ushort* __restrict__ Wlo,
                             const float* __restrict__ bias, float* __restrict__ C) {
  const int bid = blockIdx.x;
  mfma_tile128<1024>(Ahi, Alo, Whi, Wlo, bias, C, Nn, (bid % 200) * 128, (bid / 200) * 128);
}

__launch_bounds__(256)
__global__ void k_q_mfma(const ushort* __restrict__ hh, const ushort* __restrict__ hl,
                         const ushort* __restrict__ WqH, const ushort* __restrict__ WqL,
                         const float* __restrict__ bq, float* __restrict__ q) {
  mfma_tile128<512>(hh, hl, WqH, WqL, bq, q, 512, 0, blockIdx.x * 128);
}

// ---------------------------------------------------------------------------
// Fused GRU gates + pointwise via split-bf16 MFMA.
// Block: 128 b-rows x 32 j-cols (grid 16). Computes xr/xz/xn (K=1024, A=s_row)
// and hr/hz/hn (K=512, A=h), then applies the GRU update in the epilogue
// (each lane owns matching (b,j) in all 6 accumulators). Writes h fp32 + hi/lo.
__launch_bounds__(256)
__global__ void k_gates(const ushort* __restrict__ sxh, const ushort* __restrict__ sxl,
                        const float* __restrict__ hOld,
                        const ushort* __restrict__ hh, const ushort* __restrict__ hl,
                        const ushort* __restrict__ WihH, const ushort* __restrict__ WihL,
                        const ushort* __restrict__ WhhH, const ushort* __restrict__ WhhL,
                        const float* __restrict__ b_ih, const float* __restrict__ b_hh,
                        float* __restrict__ hNew, ushort* __restrict__ hhN,
                        ushort* __restrict__ hlN) {
  __shared__ __align__(16) ushort sAh[128 * 32];
  __shared__ __align__(16) ushort sAl[128 * 32];
  __shared__ __align__(16) ushort sWh[96 * 32];   // 3 gates x 32 j rows
  __shared__ __align__(16) ushort sWl[96 * 32];

  const int j0 = blockIdx.x * 32;
  const int tid = threadIdx.x, wave = tid >> 6, lane = tid & 63;
  const int wy = wave * 32;                       // wave covers 32 b-rows
  const int lm = lane & 15, lq = lane >> 4;
  const int fs = (lq ^ ((lm >> 1) & 3)) * 8;

  // A staging: 512 slots, 2/thread (slots tid, tid+256); dest = wavebase+lane*16
  const int rA0 = tid >> 2;
  const int cA0 = ((tid & 3) ^ ((rA0 >> 1) & 3)) * 8;
  const int SA1 = tid + 256;
  const int rA1 = SA1 >> 2;
  const int cA1 = ((SA1 & 3) ^ ((rA1 >> 1) & 3)) * 8;
  // W staging: 384 slots (96 rows): slot tid for all, slot tid+256 for tid<128
  const int gw0 = (rA0 >> 5) * 512 + j0 + (rA0 & 31);   // W row for slot tid
  const int gw1 = (rA1 >> 5) * 512 + j0 + (rA1 & 31);   // W row for slot tid+256
  const bool w1on = tid < 128;                           // wave-uniform guard

  f32x4 ax[3][2][2] = {};
  f32x4 ag[3][2][2] = {};

  // ---- X phase: gates from s_row, K=1024
  for (int ks = 0; ks < 32; ++ks) {
    const int ko = ks * 32;
    gld_lds16(sxh + (size_t)rA0 * 1024 + ko + cA0, &sAh[tid * 8]);
    gld_lds16(sxh + (size_t)rA1 * 1024 + ko + cA1, &sAh[SA1 * 8]);
    gld_lds16(sxl + (size_t)rA0 * 1024 + ko + cA0, &sAl[tid * 8]);
    gld_lds16(sxl + (size_t)rA1 * 1024 + ko + cA1, &sAl[SA1 * 8]);
    gld_lds16(WihH + (size_t)gw0 * 1024 + ko + cA0, &sWh[tid * 8]);
    gld_lds16(WihL + (size_t)gw0 * 1024 + ko + cA0, &sWl[tid * 8]);
    if (w1on) {
      gld_lds16(WihH + (size_t)gw1 * 1024 + ko + cA1, &sWh[SA1 * 8]);
      gld_lds16(WihL + (size_t)gw1 * 1024 + ko + cA1, &sWl[SA1 * 8]);
    }
    __syncthreads();

    bf16x8 fah[2], fal[2];
    #pragma unroll
    for (int mi = 0; mi < 2; ++mi) {
      const int o = (wy + mi * 16 + lm) * 32 + fs;
      fah[mi] = *(const bf16x8*)&sAh[o];
      fal[mi] = *(const bf16x8*)&sAl[o];
    }
    #pragma unroll
    for (int g = 0; g < 3; ++g)
      #pragma unroll
      for (int ni = 0; ni < 2; ++ni) {
        const int o = (g * 32 + ni * 16 + lm) * 32 + fs;
        bf16x8 fbh = *(const bf16x8*)&sWh[o];
        bf16x8 fbl = *(const bf16x8*)&sWl[o];
        #pragma unroll
        for (int mi = 0; mi < 2; ++mi) {
          ax[g][mi][ni] = __builtin_amdgcn_mfma_f32_16x16x32_bf16(fah[mi], fbh, ax[g][mi][ni], 0, 0, 0);
          ax[g][mi][ni] = __builtin_amdgcn_mfma_f32_16x16x32_bf16(fah[mi], fbl, ax[g][mi][ni], 0, 0, 0);
          ax[g][mi][ni] = __builtin_amdgcn_mfma_f32_16x16x32_bf16(fal[mi], fbh, ax[g][mi][ni], 0, 0, 0);
        }
      }
    __syncthreads();
  }

  // ---- H phase: gates from h, K=512
  for (int ks = 0; ks < 16; ++ks) {
    const int ko = ks * 32;
    gld_lds16(hh + (size_t)rA0 * 512 + ko + cA0, &sAh[tid * 8]);
    gld_lds16(hh + (size_t)rA1 * 512 + ko + cA1, &sAh[SA1 * 8]);
    gld_lds16(hl + (size_t)rA0 * 512 + ko + cA0, &sAl[tid * 8]);
    gld_lds16(hl + (size_t)rA1 * 512 + ko + cA1, &sAl[SA1 * 8]);
    gld_lds16(WhhH + (size_t)gw0 * 512 + ko + cA0, &sWh[tid * 8]);
    gld_lds16(WhhL + (size_t)gw0 * 512 + ko + cA0, &sWl[tid * 8]);
    if (w1on) {
      gld_lds16(WhhH + (size_t)gw1 * 512 + ko + cA1, &sWh[SA1 * 8]);
      gld_lds16(WhhL + (size_t)gw1 * 512 + ko + cA1, &sWl[SA1 * 8]);
    }
    __syncthreads();

    bf16x8 fah[2], fal[2];
    #pragma unroll
    for (int mi = 0; mi < 2; ++mi) {
      const int o = (wy + mi * 16 + lm) * 32 + fs;
      fah[mi] = *(const bf16x8*)&sAh[o];
      fal[mi] = *(const bf16x8*)&sAl[o];
    }
    #pragma unroll
    for (int g = 0; g < 3; ++g)
      #pragma unroll
      for (int ni = 0; ni < 2; ++ni) {
        const int o = (g * 32 + ni * 16 + lm) * 32 + fs;
        bf16x8 fbh = *(const bf16x8*)&sWh[o];
        bf16x8 fbl = *(const bf16x8*)&sWl[o];
        #pragma unroll
        for (int mi = 0; mi < 2; ++mi) {
          ag[g][mi][ni] = __builtin_amdgcn_mfma_f32_16x16x32_bf16(fah[mi], fbh, ag[g][mi][ni], 0, 0, 0);
          ag[g][mi][ni] = __builtin_amdgcn_mfma_f32_16x16x32_bf16(fah[mi], fbl, ag[g][mi][ni], 0, 0, 0);
          ag[g][mi][ni] = __builtin_amdgcn_mfma_f32_16x16x32_bf16(fal[mi], fbh, ag[g][mi][ni], 0, 0, 0);
        }
      }
    __syncthreads();
  }

  // ---- epilogue: GRU pointwise, write h fp32 + hi/lo split
  #pragma unroll
  for (int ni = 0; ni < 2; ++ni) {
    const int j = j0 + ni * 16 + lm;
    const float bir = b_ih[j], biz = b_ih[512 + j], bin = b_ih[1024 + j];
    const float bhr = b_hh[j], bhz = b_hh[512 + j], bhn = b_hh[1024 + j];
    #pragma unroll
    for (int mi = 0; mi < 2; ++mi) {
      const int rbase = wy + mi * 16 + lq * 4;
      #pragma unroll
      for (int rr = 0; rr < 4; ++rr) {
        const int b = rbase + rr;
        float xr = ax[0][mi][ni][rr] + bir, hr = ag[0][mi][ni][rr] + bhr;
        float xz = ax[1][mi][ni][rr] + biz, hz = ag[1][mi][ni][rr] + bhz;
        float xn = ax[2][mi][ni][rr] + bin, hn = ag[2][mi][ni][rr] + bhn;
        float r = 1.f / (1.f + expf(-(xr + hr)));
        float z = 1.f / (1.f + expf(-(xz + hz)));
        float n = tanhf(xn + r * hn);
        float hv = hOld[(size_t)b * 512 + j];
        float hw = (1.f - z) * n + z * hv;
        hNew[(size_t)b * 512 + j] = hw;
        ushort hbf = f2bf(hw);
        hhN[(size_t)b * 512 + j] = hbf;
        hlN[(size_t)b * 512 + j] = f2bf(hw - bf2f(hbf));
      }
    }
  }
}

// ---------------------------------------------------------------------------
// score[b,l] = sum_a tanh(q[b,a] + dproj[b*L+l,a]) * ws[a] + bs; mask
__launch_bounds__(256)
__global__ void k_score(const float* __restrict__ dproj, const float* __restrict__ q,
                        const float* __restrict__ wsv, const float* __restrict__ bsv,
                        const int* __restrict__ mask, float* __restrict__ scoresf,
                        float* __restrict__ outScores, int t) {
  int w = blockIdx.x * 4 + (threadIdx.x >> 6);   // 0..25599
  int lane = threadIdx.x & 63;
  int b = w / Ln, l = w % Ln;
  const float4* dp4 = (const float4*)(dproj + (size_t)w * Nn);
  const float4* q4  = (const float4*)(q + (size_t)b * Nn);
  const float4* ws4 = (const float4*)wsv;

  float sum = 0.f;
  #pragma unroll
  for (int i = 0; i < 2; ++i) {
    int idx = lane + i * 64;
    float4 d = dp4[idx], qq = q4[idx], wv = ws4[idx];
    sum += tanhf(qq.x + d.x) * wv.x + tanhf(qq.y + d.y) * wv.y
         + tanhf(qq.z + d.z) * wv.z + tanhf(qq.w + d.w) * wv.w;
  }
  #pragma unroll
  for (int off = 32; off > 0; off >>= 1) sum += __shfl_xor(sum, off, 64);

  if (lane == 0) {
    float v = sum + bsv[0];
    if (mask[w]) v = -1000000.0f;
    scoresf[w] = v;
    outScores[(size_t)b * (Tn * Ln) + t * Ln + l] = v;
  }
}

// ---------------------------------------------------------------------------
// per-batch argmax (first-index tie-break), update mask, gather selected row
// from fp32 sent, splitting to bf16 hi/lo on the fly
__launch_bounds__(256)
__global__ void k_argmax(const float* __restrict__ scoresf,
                         const float* __restrict__ sent,
                         ushort* __restrict__ s_rowh, ushort* __restrict__ s_rowl,
                         int* __restrict__ mask, float* __restrict__ outSel, int t) {
  int b = blockIdx.x;
  __shared__ int s_idx;
  int tid = threadIdx.x;
  if (tid < 64) {
    const float* sc = scoresf + (size_t)b * Ln;
    float best = -3.0e38f; int bi = 0;
    for (int l = tid; l < Ln; l += 64) {
      float v = sc[l];
      if (v > best) { best = v; bi = l; }
    }
    #pragma unroll
    for (int off = 32; off > 0; off >>= 1) {
      float ov = __shfl_down(best, off, 64);
      int   oi = __shfl_down(bi,   off, 64);
      if (ov > best || (ov == best && oi < bi)) { best = ov; bi = oi; }
    }
    if (tid == 0) s_idx = bi;
  }
  __syncthreads();
  int idx = s_idx;
  const float* src = sent + ((size_t)b * Ln + idx) * D2n;
  int k = tid * 4;                               // 256 threads x 4 = 1024
  float4 v = *(const float4*)(src + k);
  ushort4 hvec, lvec;
  hvec.x = f2bf(v.x); lvec.x = f2bf(v.x - bf2f(hvec.x));
  hvec.y = f2bf(v.y); lvec.y = f2bf(v.y - bf2f(hvec.y));
  hvec.z = f2bf(v.z); lvec.z = f2bf(v.z - bf2f(hvec.z));
  hvec.w = f2bf(v.w); lvec.w = f2bf(v.w - bf2f(hvec.w));
  *(ushort4*)(s_rowh + (size_t)b * 1024 + k) = hvec;
  *(ushort4*)(s_rowl + (size_t)b * 1024 + k) = lvec;
  if (tid == 0) {
    mask[b * Ln + idx] = 1;
    outSel[(size_t)b * Tn + t] = (float)idx;
  }
}

// ---------------------------------------------------------------------------
extern "C" void kernel_launch(void* const* d_in, const int* in_sizes, int n_in,
                              void* d_out, int out_size, void* d_ws, size_t ws_size,
                              hipStream_t stream) {
  const float* sent = (const float*)d_in[0];
  const float* h0_w = (const float*)d_in[1];
  const float* h0_b = (const float*)d_in[2];
  const float* w_ih = (const float*)d_in[3];
  const float* w_hh = (const float*)d_in[4];
  const float* b_ih = (const float*)d_in[5];
  const float* b_hh = (const float*)d_in[6];
  const float* wq   = (const float*)d_in[7];
  const float* bq   = (const float*)d_in[8];
  const float* wd   = (const float*)d_in[9];
  const float* bd   = (const float*)d_in[10];
  const float* wsv  = (const float*)d_in[11];
  const float* bsv  = (const float*)d_in[12];

  // ---- workspace layout: total 160.6 MB < R3's proven 162.5 MB ----
  float* wsf     = (float*)d_ws;
  float* d_proj  = wsf;                       // 13,107,200 f (52.4 MB)
  float* hA      = d_proj + 13107200;         // 65,536 f
  float* hB      = hA + 65536;                // 65,536 f
  float* lastb   = hB + 65536;                // 65,536 f
  float* q       = lastb + 65536;             // 65,536 f
  float* scoresf = q + 65536;                 // 25,600 f
  int*   mask    = (int*)(scoresf + 25600);   // 25,600 int
  ushort* Whi    = (ushort*)(mask + 25600);   // 524,288 us
  ushort* Wlo    = Whi + 524288;              // 524,288 us
  ushort* Ahi    = Wlo + 524288;              // 26,214,400 us (52.4 MB)
  ushort* Alo    = Ahi + 26214400;            // 26,214,400 us (52.4 MB)

  // ---- ALIASED into the Ahi region: Ahi/Alo are dead after k_dproj_mfma.
  // All writes to these buffers are stream-ordered AFTER k_dproj_mfma.
  ushort* WihH   = Ahi;                       // 1,572,864 us
  ushort* WihL   = WihH + 1572864;            // 1,572,864
  ushort* WhhH   = WihL + 1572864;            // 786,432
  ushort* WhhL   = WhhH + 786432;             // 786,432
  ushort* WqH    = WhhL + 786432;             // 262,144
  ushort* WqL    = WqH + 262144;              // 262,144
  ushort* hhA    = WqL + 262144;              // 65,536
  ushort* hlA    = hhA + 65536;
  ushort* hhB    = hlA + 65536;
  ushort* hlB    = hhB + 65536;
  ushort* s_rowh = hlB + 65536;               // 131,072
  ushort* s_rowl = s_rowh + 131072;           // 131,072  (sum 5.77M us << 26.2M)

  float* outScores = (float*)d_out;                       // (B, T, L) fp32
  float* outSel    = outScores + (size_t)Bn * Tn * Ln;    // (B, T) fp32

  hipMemsetAsync(mask, 0, 25600 * sizeof(int), stream);

  // ---- preamble (Ahi/Alo live) ----
  k_gather_lastb<<<256, 256, 0, stream>>>(sent, lastb);
  k_small_gemm<512, 1><<<dim3(8, 8), 256, 0, stream>>>(lastb, h0_w, h0_b, hA, 512);
  k_split<<<512,   256, 0, stream>>>(wd, Whi, Wlo);
  k_split<<<25600, 256, 0, stream>>>(sent, Ahi, Alo);
  k_dproj_mfma<<<800, 256, 0, stream>>>(Ahi, Alo, Whi, Wlo, bd, d_proj);

  // ---- Ahi/Alo now dead: build T-loop buffers in the alias region ----
  hipMemsetAsync(s_rowh, 0, 2 * 131072 * sizeof(ushort), stream);  // s_prev(0)=0
  k_split<<<1536,  256, 0, stream>>>(w_ih, WihH, WihL);
  k_split<<<768,   256, 0, stream>>>(w_hh, WhhH, WhhL);
  k_split<<<256,   256, 0, stream>>>(wq, WqH, WqL);
  k_split<<<64,    256, 0, stream>>>(hA, hhA, hlA);       // h0 split

  float* hc = hA;  ushort* hhc = hhA; ushort* hlc = hlA;
  float* hn = hB;  ushort* hhn = hhB; ushort* hln = hlB;
  for (int t = 0; t < Tn; ++t) {
    k_gates<<<16, 256, 0, stream>>>(s_rowh, s_rowl, hc, hhc, hlc,
                                    WihH, WihL, WhhH, WhhL, b_ih, b_hh,
                                    hn, hhn, hln);
    k_q_mfma<<<4, 256, 0, stream>>>(hhn, hln, WqH, WqL, bq, q);
    k_score<<<6400, 256, 0, stream>>>(d_proj, q, wsv, bsv, mask, scoresf, outScores, t);
    k_argmax<<<128, 256, 0, stream>>>(scoresf, sent, s_rowh, s_rowl, mask, outSel, t);
    float* tf = hc; hc = hn; hn = tf;
    ushort* t1 = hhc; hhc = hhn; hhn = t1;
    ushort* t2 = hlc; hlc = hln; hln = t2;
  }
}

// Round 8
// 569.973 us; speedup vs baseline: 1.9293x; 1.0398x over previous
//
#include <hip/hip_runtime.h>
#include <hip/hip_bf16.h>

// Problem constants
constexpr int Bn  = 128;   // batch
constexpr int Ln  = 200;   // sentences
constexpr int D2n = 1024;  // 2*SH
constexpr int G3n = 1536;  // 3*EH
constexpr int Tn  = 3;
constexpr int Nn  = 512;   // A (attention dim) == d_proj cols
constexpr int Kn  = 1024;  // d_proj K

typedef unsigned short ushort;
typedef float f32x4 __attribute__((ext_vector_type(4)));
typedef __bf16 bf16x8 __attribute__((ext_vector_type(8)));

__device__ __forceinline__ ushort f2bf(float f) {   // RNE float->bf16
  unsigned u = __float_as_uint(f);
  unsigned r = (u + 0x7fffu + ((u >> 16) & 1u)) >> 16;
  return (ushort)r;
}
__device__ __forceinline__ float bf2f(ushort h) {
  return __uint_as_float(((unsigned)h) << 16);
}

__device__ __forceinline__ void gld_lds16(const ushort* g, ushort* l) {
  __builtin_amdgcn_global_load_lds(
      (const __attribute__((address_space(1))) unsigned int*)g,
      (__attribute__((address_space(3))) unsigned int*)l, 16, 0, 0);
}

// fast tanh: (e^{2x}-1)/(e^{2x}+1), clamped; err ~1e-6, << bf16-split noise
__device__ __forceinline__ float ftanh(float x) {
  float cx = fminf(fmaxf(x, -15.f), 15.f);
  float e  = __expf(2.f * cx);
  return (e - 1.f) * __builtin_amdgcn_rcpf(e + 1.f);
}

// ---------------------------------------------------------------------------
// split fp32 -> hi/lo bf16 (wd, sent)
__global__ void k_split(const float* __restrict__ W, ushort* __restrict__ hi,
                        ushort* __restrict__ lo) {
  int i = blockIdx.x * 256 + threadIdx.x;        // float4 index
  float4 v = ((const float4*)W)[i];
  ushort4 h, l;
  h.x = f2bf(v.x); l.x = f2bf(v.x - bf2f(h.x));
  h.y = f2bf(v.y); l.y = f2bf(v.y - bf2f(h.y));
  h.z = f2bf(v.z); l.z = f2bf(v.z - bf2f(h.z));
  h.w = f2bf(v.w); l.w = f2bf(v.w - bf2f(h.w));
  ((ushort4*)hi)[i] = h;
  ((ushort4*)lo)[i] = l;
}

// combined weight split: w_ih (393216 f4) + w_hh (196608 f4) + wq (65536 f4)
__global__ void k_split3(const float* __restrict__ w_ih, const float* __restrict__ w_hh,
                         const float* __restrict__ wq,
                         ushort* __restrict__ WihH, ushort* __restrict__ WihL,
                         ushort* __restrict__ WhhH, ushort* __restrict__ WhhL,
                         ushort* __restrict__ WqH, ushort* __restrict__ WqL) {
  int i = blockIdx.x * 256 + threadIdx.x;        // 0..655359
  const float* src; ushort* hi; ushort* lo; int off;
  if (i < 393216)      { src = w_ih; hi = WihH; lo = WihL; off = i; }
  else if (i < 589824) { src = w_hh; hi = WhhH; lo = WhhL; off = i - 393216; }
  else                 { src = wq;   hi = WqH;  lo = WqL;  off = i - 589824; }
  float4 v = ((const float4*)src)[off];
  ushort4 h, l;
  h.x = f2bf(v.x); l.x = f2bf(v.x - bf2f(h.x));
  h.y = f2bf(v.y); l.y = f2bf(v.y - bf2f(h.y));
  h.z = f2bf(v.z); l.z = f2bf(v.z - bf2f(h.z));
  h.w = f2bf(v.w); l.w = f2bf(v.w - bf2f(h.w));
  ((ushort4*)hi)[off] = h;
  ((ushort4*)lo)[off] = l;
}

// ---------------------------------------------------------------------------
// h0 = tanh(last_back @ h0_w^T + h0_b), gather fused, writes fp32 + hi/lo split
__launch_bounds__(256)
__global__ void k_h0(const float* __restrict__ sent, const float* __restrict__ W,
                     const float* __restrict__ bias, float* __restrict__ out,
                     ushort* __restrict__ outh, ushort* __restrict__ outl) {
  __shared__ float s[16 * 512];
  const int b0 = blockIdx.y * 16;
  const int jl = threadIdx.x & 63;
  const int j  = blockIdx.x * 64 + jl;
  const int bg = (threadIdx.x >> 6) * 4;

  for (int i = threadIdx.x; i < 2048; i += 256) {   // 16 rows x 128 float4
    int r = i >> 7, c = i & 127;
    ((float4*)s)[i] = *(const float4*)(sent + (size_t)(b0 + r) * (Ln * D2n) + 512 + c * 4);
  }
  __syncthreads();

  const float4* w4 = (const float4*)(W + (size_t)j * 512);
  const float4* r0 = (const float4*)(s + (size_t)(bg + 0) * 512);
  const float4* r1 = (const float4*)(s + (size_t)(bg + 1) * 512);
  const float4* r2 = (const float4*)(s + (size_t)(bg + 2) * 512);
  const float4* r3 = (const float4*)(s + (size_t)(bg + 3) * 512);

  float acc0 = 0.f, acc1 = 0.f, acc2 = 0.f, acc3 = 0.f;
  #pragma unroll 4
  for (int k4 = 0; k4 < 128; ++k4) {
    float4 wv = w4[k4];
    float4 a;
    a = r0[k4]; acc0 += wv.x*a.x + wv.y*a.y + wv.z*a.z + wv.w*a.w;
    a = r1[k4]; acc1 += wv.x*a.x + wv.y*a.y + wv.z*a.z + wv.w*a.w;
    a = r2[k4]; acc2 += wv.x*a.x + wv.y*a.y + wv.z*a.z + wv.w*a.w;
    a = r3[k4]; acc3 += wv.x*a.x + wv.y*a.y + wv.z*a.z + wv.w*a.w;
  }
  float bb = bias[j];
  float accs[4] = {acc0, acc1, acc2, acc3};
  #pragma unroll
  for (int i = 0; i < 4; ++i) {
    float v = tanhf(accs[i] + bb);
    size_t o = (size_t)(b0 + bg + i) * 512 + j;
    out[o] = v;
    ushort hv = f2bf(v);
    outh[o] = hv;
    outl[o] = f2bf(v - bf2f(hv));
  }
}

// ---------------------------------------------------------------------------
// Shared 128x128-tile split-bf16 MFMA body (proven: 0 bank conflicts).
template<int KK>
__device__ __forceinline__ void mfma_tile128(
    const ushort* __restrict__ Ah, const ushort* __restrict__ Al,
    const ushort* __restrict__ Bh, const ushort* __restrict__ Bl,
    const float* __restrict__ bias, float* __restrict__ C, int ldc,
    int m0, int n0) {
  __shared__ __align__(16) ushort sAh[128 * 32];
  __shared__ __align__(16) ushort sAl[128 * 32];
  __shared__ __align__(16) ushort sBh[128 * 32];
  __shared__ __align__(16) ushort sBl[128 * 32];

  const int tid  = threadIdx.x;
  const int wave = tid >> 6, lane = tid & 63;
  const int wy = (wave >> 1) * 64, wx = (wave & 1) * 64;
  const int lm = lane & 15, lq = lane >> 4;
  const int fs = (lq ^ ((lm >> 1) & 3)) * 8;     // swizzled 16B slot

  const int S0 = (wave * 2 + 0) * 64 + lane;
  const int S1 = (wave * 2 + 1) * 64 + lane;
  const int r0 = S0 >> 2, r1 = S1 >> 2;
  const int c0 = ((S0 & 3) ^ ((r0 >> 1) & 3)) * 8;
  const int c1 = ((S1 & 3) ^ ((r1 >> 1) & 3)) * 8;
  const ushort* pAh0 = Ah + (size_t)(m0 + r0) * KK + c0;
  const ushort* pAh1 = Ah + (size_t)(m0 + r1) * KK + c1;
  const ushort* pAl0 = Al + (size_t)(m0 + r0) * KK + c0;
  const ushort* pAl1 = Al + (size_t)(m0 + r1) * KK + c1;
  const ushort* pBh0 = Bh + (size_t)(n0 + r0) * KK + c0;
  const ushort* pBh1 = Bh + (size_t)(n0 + r1) * KK + c1;
  const ushort* pBl0 = Bl + (size_t)(n0 + r0) * KK + c0;
  const ushort* pBl1 = Bl + (size_t)(n0 + r1) * KK + c1;
  ushort* dA0 = &sAh[S0 * 8]; ushort* dA1 = &sAh[S1 * 8];
  ushort* dL0 = &sAl[S0 * 8]; ushort* dL1 = &sAl[S1 * 8];
  ushort* dB0 = &sBh[S0 * 8]; ushort* dB1 = &sBh[S1 * 8];
  ushort* dC0 = &sBl[S0 * 8]; ushort* dC1 = &sBl[S1 * 8];

  f32x4 acc[4][4] = {};

  for (int ks = 0; ks < KK / 32; ++ks) {
    const int ko = ks * 32;
    gld_lds16(pAh0 + ko, dA0); gld_lds16(pAh1 + ko, dA1);
    gld_lds16(pAl0 + ko, dL0); gld_lds16(pAl1 + ko, dL1);
    gld_lds16(pBh0 + ko, dB0); gld_lds16(pBh1 + ko, dB1);
    gld_lds16(pBl0 + ko, dC0); gld_lds16(pBl1 + ko, dC1);
    __syncthreads();

    bf16x8 ah[4], al[4], bh[4], bl[4];
    #pragma unroll
    for (int mi = 0; mi < 4; ++mi) {
      const int o = (wy + mi * 16 + lm) * 32 + fs;
      ah[mi] = *(const bf16x8*)&sAh[o];
      al[mi] = *(const bf16x8*)&sAl[o];
    }
    #pragma unroll
    for (int ni = 0; ni < 4; ++ni) {
      const int o = (wx + ni * 16 + lm) * 32 + fs;
      bh[ni] = *(const bf16x8*)&sBh[o];
      bl[ni] = *(const bf16x8*)&sBl[o];
    }
    #pragma unroll
    for (int mi = 0; mi < 4; ++mi)
      #pragma unroll
      for (int ni = 0; ni < 4; ++ni) {
        acc[mi][ni] = __builtin_amdgcn_mfma_f32_16x16x32_bf16(ah[mi], bh[ni], acc[mi][ni], 0, 0, 0);
        acc[mi][ni] = __builtin_amdgcn_mfma_f32_16x16x32_bf16(ah[mi], bl[ni], acc[mi][ni], 0, 0, 0);
        acc[mi][ni] = __builtin_amdgcn_mfma_f32_16x16x32_bf16(al[mi], bh[ni], acc[mi][ni], 0, 0, 0);
      }
    __syncthreads();
  }

  #pragma unroll
  for (int ni = 0; ni < 4; ++ni) {
    int col = n0 + wx + ni * 16 + lm;
    float bb = bias[col];
    #pragma unroll
    for (int mi = 0; mi < 4; ++mi) {
      int rbase = m0 + wy + mi * 16 + lq * 4;
      #pragma unroll
      for (int r = 0; r < 4; ++r)
        C[(size_t)(rbase + r) * ldc + col] = acc[mi][ni][r] + bb;
    }
  }
}

__launch_bounds__(256)
__global__ void k_dproj_mfma(const ushort* __restrict__ Ahi, const ushort* __restrict__ Alo,
                             const ushort* __restrict__ Whi, const ushort* __restrict__ Wlo,
                             const float* __restrict__ bias, float* __restrict__ C) {
  const int bid = blockIdx.x;
  mfma_tile128<1024>(Ahi, Alo, Whi, Wlo, bias, C, Nn, (bid % 200) * 128, (bid / 200) * 128);
}

__launch_bounds__(256)
__global__ void k_q_mfma(const ushort* __restrict__ hh, const ushort* __restrict__ hl,
                         const ushort* __restrict__ WqH, const ushort* __restrict__ WqL,
                         const float* __restrict__ bq, float* __restrict__ q) {
  mfma_tile128<512>(hh, hl, WqH, WqL, bq, q, 512, 0, blockIdx.x * 128);
}

// ---------------------------------------------------------------------------
// Fused GRU gates + pointwise, v2: grid 64 = 2 b-halves x 32 j-tiles(16),
// BK=64 via two proven-swizzle 32-col sub-tiles -> 24 K-steps (was 48),
// 4x CU coverage. Wave covers 16 b-rows; per-lane acc: 3 gates x f32x4.
__launch_bounds__(256)
__global__ void k_gates(const ushort* __restrict__ sxh, const ushort* __restrict__ sxl,
                        const float* __restrict__ hOld,
                        const ushort* __restrict__ hh, const ushort* __restrict__ hl,
                        const ushort* __restrict__ WihH, const ushort* __restrict__ WihL,
                        const ushort* __restrict__ WhhH, const ushort* __restrict__ WhhL,
                        const float* __restrict__ b_ih, const float* __restrict__ b_hh,
                        float* __restrict__ hNew, ushort* __restrict__ hhN,
                        ushort* __restrict__ hlN) {
  __shared__ __align__(16) ushort sAh[2][64 * 32];
  __shared__ __align__(16) ushort sAl[2][64 * 32];
  __shared__ __align__(16) ushort sWh[2][48 * 32];  // 3 gates x 16 j rows
  __shared__ __align__(16) ushort sWl[2][48 * 32];

  const int bb  = blockIdx.x >> 5;                // 0..1 (batch half)
  const int j0  = (blockIdx.x & 31) * 16;         // j tile
  const int rb0 = bb * 64;
  const int tid = threadIdx.x, wave = tid >> 6, lane = tid & 63;
  const int wy = wave * 16;                       // wave's 16 b-rows
  const int lm = lane & 15, lq = lane >> 4;
  const int fs = (lq ^ ((lm >> 1) & 3)) * 8;

  // A staging: 256 slots (64 rows x 4), 1/thread/sub-tile
  const int rA = tid >> 2;                        // local row 0..63
  const int cA = ((tid & 3) ^ ((rA >> 1) & 3)) * 8;
  // W staging: 192 slots (48 rows x 4), threads 0..191 (waves 0-2, uniform)
  const bool wOn = tid < 192;
  const int gw = (rA >> 4) * 512 + j0 + (rA & 15); // rA doubles as rW (0..47)

  f32x4 ax[3] = {};
  f32x4 ag[3] = {};

  // ---- X phase: gates from s_row, K=1024, 16 steps of BK=64
  for (int ks = 0; ks < 16; ++ks) {
    const int ko = ks * 64;
    #pragma unroll
    for (int kk = 0; kk < 2; ++kk) {
      gld_lds16(sxh + (size_t)(rb0 + rA) * 1024 + ko + kk * 32 + cA, &sAh[kk][tid * 8]);
      gld_lds16(sxl + (size_t)(rb0 + rA) * 1024 + ko + kk * 32 + cA, &sAl[kk][tid * 8]);
      if (wOn) {
        gld_lds16(WihH + (size_t)gw * 1024 + ko + kk * 32 + cA, &sWh[kk][tid * 8]);
        gld_lds16(WihL + (size_t)gw * 1024 + ko + kk * 32 + cA, &sWl[kk][tid * 8]);
      }
    }
    __syncthreads();
    #pragma unroll
    for (int kk = 0; kk < 2; ++kk) {
      const int oA = (wy + lm) * 32 + fs;
      bf16x8 fah = *(const bf16x8*)&sAh[kk][oA];
      bf16x8 fal = *(const bf16x8*)&sAl[kk][oA];
      #pragma unroll
      for (int g = 0; g < 3; ++g) {
        const int oW = (g * 16 + lm) * 32 + fs;
        bf16x8 fbh = *(const bf16x8*)&sWh[kk][oW];
        bf16x8 fbl = *(const bf16x8*)&sWl[kk][oW];
        ax[g] = __builtin_amdgcn_mfma_f32_16x16x32_bf16(fah, fbh, ax[g], 0, 0, 0);
        ax[g] = __builtin_amdgcn_mfma_f32_16x16x32_bf16(fah, fbl, ax[g], 0, 0, 0);
        ax[g] = __builtin_amdgcn_mfma_f32_16x16x32_bf16(fal, fbh, ax[g], 0, 0, 0);
      }
    }
    __syncthreads();
  }

  // ---- H phase: gates from h, K=512, 8 steps of BK=64
  for (int ks = 0; ks < 8; ++ks) {
    const int ko = ks * 64;
    #pragma unroll
    for (int kk = 0; kk < 2; ++kk) {
      gld_lds16(hh + (size_t)(rb0 + rA) * 512 + ko + kk * 32 + cA, &sAh[kk][tid * 8]);
      gld_lds16(hl + (size_t)(rb0 + rA) * 512 + ko + kk * 32 + cA, &sAl[kk][tid * 8]);
      if (wOn) {
        gld_lds16(WhhH + (size_t)gw * 512 + ko + kk * 32 + cA, &sWh[kk][tid * 8]);
        gld_lds16(WhhL + (size_t)gw * 512 + ko + kk * 32 + cA, &sWl[kk][tid * 8]);
      }
    }
    __syncthreads();
    #pragma unroll
    for (int kk = 0; kk < 2; ++kk) {
      const int oA = (wy + lm) * 32 + fs;
      bf16x8 fah = *(const bf16x8*)&sAh[kk][oA];
      bf16x8 fal = *(const bf16x8*)&sAl[kk][oA];
      #pragma unroll
      for (int g = 0; g < 3; ++g) {
        const int oW = (g * 16 + lm) * 32 + fs;
        bf16x8 fbh = *(const bf16x8*)&sWh[kk][oW];
        bf16x8 fbl = *(const bf16x8*)&sWl[kk][oW];
        ag[g] = __builtin_amdgcn_mfma_f32_16x16x32_bf16(fah, fbh, ag[g], 0, 0, 0);
        ag[g] = __builtin_amdgcn_mfma_f32_16x16x32_bf16(fah, fbl, ag[g], 0, 0, 0);
        ag[g] = __builtin_amdgcn_mfma_f32_16x16x32_bf16(fal, fbh, ag[g], 0, 0, 0);
      }
    }
    __syncthreads();
  }

  // ---- epilogue: GRU pointwise, write h fp32 + hi/lo split
  const int j = j0 + lm;
  const float bir = b_ih[j], biz = b_ih[512 + j], bin = b_ih[1024 + j];
  const float bhr = b_hh[j], bhz = b_hh[512 + j], bhn = b_hh[1024 + j];
  #pragma unroll
  for (int rr = 0; rr < 4; ++rr) {
    const int b = rb0 + wy + lq * 4 + rr;
    float xr = ax[0][rr] + bir, hr = ag[0][rr] + bhr;
    float xz = ax[1][rr] + biz, hz = ag[1][rr] + bhz;
    float xn = ax[2][rr] + bin, hn = ag[2][rr] + bhn;
    float r = 1.f / (1.f + expf(-(xr + hr)));
    float z = 1.f / (1.f + expf(-(xz + hz)));
    float n = tanhf(xn + r * hn);
    float hv = hOld[(size_t)b * 512 + j];
    float hw = (1.f - z) * n + z * hv;
    hNew[(size_t)b * 512 + j] = hw;
    ushort hbf = f2bf(hw);
    hhN[(size_t)b * 512 + j] = hbf;
    hlN[(size_t)b * 512 + j] = f2bf(hw - bf2f(hbf));
  }
}

// ---------------------------------------------------------------------------
// Fused score + argmax + select: one block per batch b.
// 4 waves x 50 rows: score[l] = sum_a ftanh(q+dproj)*ws + bs (mask applied),
// stash in LDS; wave0 argmax (first-idx tiebreak); gather+split s_row.
__launch_bounds__(256)
__global__ void k_score_argmax(const float* __restrict__ dproj, const float* __restrict__ q,
                               const float* __restrict__ wsv, const float* __restrict__ bsv,
                               const float* __restrict__ sent,
                               ushort* __restrict__ s_rowh, ushort* __restrict__ s_rowl,
                               int* __restrict__ mask, float* __restrict__ outScores,
                               float* __restrict__ outSel, int t) {
  const int b = blockIdx.x;
  const int tid = threadIdx.x, lane = tid & 63, wv = tid >> 6;
  __shared__ float ssc[Ln];
  __shared__ int s_idx;

  const float4* q4  = (const float4*)(q + (size_t)b * Nn);
  const float4* ws4 = (const float4*)wsv;
  const float4 qq0 = q4[lane],  qq1 = q4[lane + 64];
  const float4 wv0 = ws4[lane], wv1 = ws4[lane + 64];
  const float bs0 = bsv[0];

  for (int l = wv; l < Ln; l += 4) {
    const float4* dp4 = (const float4*)(dproj + ((size_t)b * Ln + l) * Nn);
    float4 d0 = dp4[lane], d1 = dp4[lane + 64];
    float sum = ftanh(qq0.x + d0.x) * wv0.x + ftanh(qq0.y + d0.y) * wv0.y
              + ftanh(qq0.z + d0.z) * wv0.z + ftanh(qq0.w + d0.w) * wv0.w
              + ftanh(qq1.x + d1.x) * wv1.x + ftanh(qq1.y + d1.y) * wv1.y
              + ftanh(qq1.z + d1.z) * wv1.z + ftanh(qq1.w + d1.w) * wv1.w;
    #pragma unroll
    for (int off = 32; off > 0; off >>= 1) sum += __shfl_xor(sum, off, 64);
    if (lane == 0) {
      float v = sum + bs0;
      if (mask[b * Ln + l]) v = -1000000.0f;
      ssc[l] = v;
      outScores[(size_t)b * (Tn * Ln) + t * Ln + l] = v;
    }
  }
  __syncthreads();

  if (tid < 64) {
    float best = -3.0e38f; int bi = 0;
    for (int l = tid; l < Ln; l += 64) {
      float v = ssc[l];
      if (v > best) { best = v; bi = l; }        // increasing l: > keeps first
    }
    #pragma unroll
    for (int off = 32; off > 0; off >>= 1) {
      float ov = __shfl_down(best, off, 64);
      int   oi = __shfl_down(bi,   off, 64);
      if (ov > best || (ov == best && oi < bi)) { best = ov; bi = oi; }
    }
    if (tid == 0) s_idx = bi;
  }
  __syncthreads();
  int idx = s_idx;
  const float* src = sent + ((size_t)b * Ln + idx) * D2n;
  int k = tid * 4;                               // 256 x 4 = 1024
  float4 v = *(const float4*)(src + k);
  ushort4 hvec, lvec;
  hvec.x = f2bf(v.x); lvec.x = f2bf(v.x - bf2f(hvec.x));
  hvec.y = f2bf(v.y); lvec.y = f2bf(v.y - bf2f(hvec.y));
  hvec.z = f2bf(v.z); lvec.z = f2bf(v.z - bf2f(hvec.z));
  hvec.w = f2bf(v.w); lvec.w = f2bf(v.w - bf2f(hvec.w));
  *(ushort4*)(s_rowh + (size_t)b * 1024 + k) = hvec;
  *(ushort4*)(s_rowl + (size_t)b * 1024 + k) = lvec;
  if (tid == 0) {
    mask[b * Ln + idx] = 1;
    outSel[(size_t)b * Tn + t] = (float)idx;
  }
}

// ---------------------------------------------------------------------------
extern "C" void kernel_launch(void* const* d_in, const int* in_sizes, int n_in,
                              void* d_out, int out_size, void* d_ws, size_t ws_size,
                              hipStream_t stream) {
  const float* sent = (const float*)d_in[0];
  const float* h0_w = (const float*)d_in[1];
  const float* h0_b = (const float*)d_in[2];
  const float* w_ih = (const float*)d_in[3];
  const float* w_hh = (const float*)d_in[4];
  const float* b_ih = (const float*)d_in[5];
  const float* b_hh = (const float*)d_in[6];
  const float* wq   = (const float*)d_in[7];
  const float* bq   = (const float*)d_in[8];
  const float* wd   = (const float*)d_in[9];
  const float* bd   = (const float*)d_in[10];
  const float* wsv  = (const float*)d_in[11];
  const float* bsv  = (const float*)d_in[12];

  // ---- workspace: main region 161.3 MB < 162.5 MB proven ----
  float* wsf     = (float*)d_ws;
  float* d_proj  = wsf;                       // 13,107,200 f
  float* hA      = d_proj + 13107200;         // 65,536 f
  float* hB      = hA + 65536;                // 65,536 f
  float* q       = hB + 65536;                // 65,536 f
  int*   mask    = (int*)(q + 65536);         // 25,600 int
  ushort* Whi    = (ushort*)(mask + 25600);   // 524,288 us
  ushort* Wlo    = Whi + 524288;              // 524,288 us
  ushort* hhA    = Wlo + 524288;              // 65,536 us
  ushort* hlA    = hhA + 65536;
  ushort* hhB    = hlA + 65536;
  ushort* hlB    = hhB + 65536;
  ushort* s_rowh = hlB + 65536;               // 131,072 us
  ushort* s_rowl = s_rowh + 131072;           // 131,072 us
  ushort* Ahi    = s_rowl + 131072;           // 26,214,400 us
  ushort* Alo    = Ahi + 26214400;            // 26,214,400 us

  // ---- aliased into Ahi (dead after k_dproj_mfma); writes stream-after dproj
  ushort* WihH   = Ahi;                       // 1,572,864 us
  ushort* WihL   = WihH + 1572864;
  ushort* WhhH   = WihL + 1572864;            // 786,432
  ushort* WhhL   = WhhH + 786432;
  ushort* WqH    = WhhL + 786432;             // 262,144
  ushort* WqL    = WqH + 262144;              // sum 5.24M us << 26.2M

  float* outScores = (float*)d_out;                       // (B, T, L) fp32
  float* outSel    = outScores + (size_t)Bn * Tn * Ln;    // (B, T) fp32

  hipMemsetAsync(mask, 0, 25600 * sizeof(int), stream);
  hipMemsetAsync(s_rowh, 0, 2 * 131072 * sizeof(ushort), stream);  // s_prev(0)=0

  // ---- preamble ----
  k_h0<<<dim3(8, 8), 256, 0, stream>>>(sent, h0_w, h0_b, hA, hhA, hlA);
  k_split<<<512,   256, 0, stream>>>(wd, Whi, Wlo);
  k_split<<<25600, 256, 0, stream>>>(sent, Ahi, Alo);
  k_dproj_mfma<<<800, 256, 0, stream>>>(Ahi, Alo, Whi, Wlo, bd, d_proj);
  k_split3<<<2560, 256, 0, stream>>>(w_ih, w_hh, wq, WihH, WihL, WhhH, WhhL, WqH, WqL);

  float* hc = hA;  ushort* hhc = hhA; ushort* hlc = hlA;
  float* hn = hB;  ushort* hhn = hhB; ushort* hln = hlB;
  for (int t = 0; t < Tn; ++t) {
    k_gates<<<64, 256, 0, stream>>>(s_rowh, s_rowl, hc, hhc, hlc,
                                    WihH, WihL, WhhH, WhhL, b_ih, b_hh,
                                    hn, hhn, hln);
    k_q_mfma<<<4, 256, 0, stream>>>(hhn, hln, WqH, WqL, bq, q);
    k_score_argmax<<<128, 256, 0, stream>>>(d_proj, q, wsv, bsv, sent,
                                            s_rowh, s_rowl, mask,
                                            outScores, outSel, t);
    float* tf = hc; hc = hn; hn = tf;
    ushort* t1 = hhc; hhc = hhn; hhn = t1;
    ushort* t2 = hlc; hlc = hln; hln = t2;
  }
}